// Round 2
// baseline (420.698 us; speedup 1.0000x reference)
//
#include <hip/hip_runtime.h>

// SelfAttnBlock: BN -> QKV 1x1conv -> full 4096x4096 attention (flash-style,
// never materialized) -> 1x1 conv -> residual.  MI355X gfx950.
//
// R2 design notes (R1 + latency fixes, no bench data yet):
//  - no-max-subtraction softmax (scores ~N(0,1.44) in exp2 domain, fp32 safe)
//  - QK^T in bf16 hi/lo split (6 MFMAs per 16x16x64) for ~2^-17 score accuracy
//  - P,V single bf16 for PV MFMA
//  - swapped-operand mfma(K,Q) -> S^T frags; P through XOR-swizzled LDS;
//    PV with A=P,B=V gives res[q][ch] directly
//  - res stored [n][i][ch]; flat view == [c2][h2][w2] needed by final conv
//  - K(t+1) software prefetch; V(t) issued before QK phase (hidden under MFMA)
//  - barrier = s_waitcnt lgkmcnt(0) + s_barrier (NO vmcnt drain -> prefetch
//    stays in flight across the barrier, T4-lite)
//  - s_setprio(1) around MFMA clusters (T5)

#define HW 4096
#define CC 64
#define NBATCH 8
// 0.125 * log2(e): fold attention scale + exp->exp2 conversion into Q
#define QSCALE 0.18033688011112042f

using f32x4 = __attribute__((ext_vector_type(4))) float;
using bf16x8 = __attribute__((ext_vector_type(8))) short;
typedef unsigned short u16;
typedef unsigned int u32;

#if __has_builtin(__builtin_amdgcn_exp2f)
#define EXP2F(v) __builtin_amdgcn_exp2f(v)
#else
#define EXP2F(v) exp2f(v)
#endif

__device__ __forceinline__ u16 f2bf(float v) {  // RNE f32->bf16
  u32 u = __float_as_uint(v);
  return (u16)((u + 0x7fffu + ((u >> 16) & 1u)) >> 16);
}
__device__ __forceinline__ float bf2f(u16 h) {
  return __uint_as_float(((u32)h) << 16);
}

// ---------- kernel 1: BN stats -> per-channel scale a, shift b (xn = x*a+b)
__global__ __launch_bounds__(256) void k_stats(const float* __restrict__ x,
                                               const float* __restrict__ gamma,
                                               const float* __restrict__ beta,
                                               float* __restrict__ sab) {
  const int c = blockIdx.x;
  const int tid = threadIdx.x;
  const float* xc = x + (size_t)c * HW;
  float s1 = 0.f, s2 = 0.f;
  for (int idx = tid; idx < NBATCH * HW; idx += 256) {
    const int nn = idx >> 12;
    const int i = idx & (HW - 1);
    const float v = xc[(size_t)nn * (CC * HW) + i];
    s1 += v;
    s2 += v * v;
  }
#pragma unroll
  for (int m = 1; m <= 32; m <<= 1) {
    s1 += __shfl_xor(s1, m);
    s2 += __shfl_xor(s2, m);
  }
  __shared__ float r1[4], r2[4];
  const int w = tid >> 6;
  if ((tid & 63) == 0) { r1[w] = s1; r2[w] = s2; }
  __syncthreads();
  if (tid == 0) {
    const float S1 = r1[0] + r1[1] + r1[2] + r1[3];
    const float S2 = r2[0] + r2[1] + r2[2] + r2[3];
    const float inv = 1.0f / (float)(NBATCH * HW);
    const float mean = S1 * inv;
    const float var = S2 * inv - mean * mean;  // biased, matches jnp.var
    const float a = rsqrtf(var + 1e-5f) * gamma[c];
    sab[c] = a;
    sab[CC + c] = beta[c] - mean * a;
  }
}

// ---------- kernel 2: fused BN-apply + Q/K/V 1x1 convs + bf16 hi/lo quantize
// outputs: QH/QL/KH/KL as [n][hw][c] bf16 ; V as [n][c][hw] bf16
__device__ __forceinline__ void mm16(const float* __restrict__ W,
                                     const float* __restrict__ B,
                                     const float* xcol, int o0, float scale,
                                     float* outv) {
#pragma unroll
  for (int oo = 0; oo < 16; ++oo) {
    const int o = o0 + oo;
    float a = B[o];                  // uniform per wave -> SGPR
#pragma unroll
    for (int c = 0; c < CC; ++c) a = fmaf(W[o * CC + c], xcol[c], a);
    outv[oo] = a * scale;
  }
}

__device__ __forceinline__ void split_store16(const float* v16, u16* dh, u16* dl) {
  u32 hi[8], lo[8];
#pragma unroll
  for (int e = 0; e < 8; ++e) {
    const u16 h0 = f2bf(v16[2 * e]), h1 = f2bf(v16[2 * e + 1]);
    const float l0 = v16[2 * e] - bf2f(h0);
    const float l1 = v16[2 * e + 1] - bf2f(h1);
    hi[e] = (u32)h0 | ((u32)h1 << 16);
    lo[e] = (u32)f2bf(l0) | ((u32)f2bf(l1) << 16);
  }
  ((uint4*)dh)[0] = *(const uint4*)&hi[0];
  ((uint4*)dh)[1] = *(const uint4*)&hi[4];
  ((uint4*)dl)[0] = *(const uint4*)&lo[0];
  ((uint4*)dl)[1] = *(const uint4*)&lo[4];
}

__global__ __launch_bounds__(256) void k_qkv(
    const float* __restrict__ x, const float* __restrict__ sab,
    const float* __restrict__ wq, const float* __restrict__ bq,
    const float* __restrict__ wk, const float* __restrict__ bk,
    const float* __restrict__ wv, const float* __restrict__ bv,
    u16* __restrict__ QH, u16* __restrict__ QL, u16* __restrict__ KH,
    u16* __restrict__ KL, u16* __restrict__ V) {
  const int n = blockIdx.x >> 6;
  const int i0 = (blockIdx.x & 63) << 6;
  __shared__ float xn[CC][64];
  const int tid = threadIdx.x;
  {
    const int p = tid & 63;
    const int c0 = (tid >> 6) << 4;
    const float* xp = x + (size_t)n * CC * HW + i0 + p;
    const float* a = sab;
    const float* b = sab + CC;
#pragma unroll
    for (int cc = 0; cc < 16; ++cc) {
      const int c = c0 + cc;
      xn[c][p] = fmaf(xp[(size_t)c * HW], a[c], b[c]);
    }
  }
  __syncthreads();
  const int w = tid >> 6;  // wave -> output-channel block (uniform W reads)
  const int p = tid & 63;
  float xcol[CC];
#pragma unroll
  for (int c = 0; c < CC; ++c) xcol[c] = xn[c][p];

  const size_t row = (size_t)n * HW + i0 + p;
  float v16[16];
  mm16(wq, bq, xcol, w * 16, QSCALE, v16);
  split_store16(v16, QH + row * CC + w * 16, QL + row * CC + w * 16);
  mm16(wk, bk, xcol, w * 16, 1.0f, v16);
  split_store16(v16, KH + row * CC + w * 16, KL + row * CC + w * 16);
  mm16(wv, bv, xcol, w * 16, 1.0f, v16);
#pragma unroll
  for (int oo = 0; oo < 16; ++oo)
    V[((size_t)n * CC + w * 16 + oo) * HW + i0 + p] = f2bf(v16[oo]);
}

// ---------- kernel 3: flash attention, QB=64 q-rows/block, KB=64 keys/step
__global__ __launch_bounds__(256) void k_attn(
    const u16* __restrict__ QH, const u16* __restrict__ QL,
    const u16* __restrict__ KH, const u16* __restrict__ KL,
    const u16* __restrict__ V, float* __restrict__ RES) {
  // XCD swizzle: keep each batch's 64 blocks on one XCD (per-batch K/V=1.5MB<L2)
  const int rb = ((blockIdx.x & 7) << 6) | (blockIdx.x >> 3);
  const int n = rb >> 6;
  const int q0 = (rb & 63) << 6;
  const int tid = threadIdx.x;
  const int w = tid >> 6;
  const int l = tid & 63;
  const int l15 = l & 15;
  const int lg = l >> 4;

  __shared__ alignas(16) u16 P[2][64][64];  // [buf][q][key^((q&7)<<3)]
  __shared__ float ZB[4][64];

  // resident Q B-frags: lane holds Q[q0+qb*16+l15][m*32+lg*8 .. +8]
  bf16x8 qh[4][2], ql[4][2];
  {
    const size_t base = ((size_t)n * HW + q0 + l15) * CC + lg * 8;
#pragma unroll
    for (int qb = 0; qb < 4; ++qb)
#pragma unroll
      for (int m = 0; m < 2; ++m) {
        const size_t off = base + (size_t)qb * 16 * CC + m * 32;
        qh[qb][m] = *(const bf16x8*)(QH + off);
        ql[qb][m] = *(const bf16x8*)(QL + off);
      }
  }

  f32x4 acc[4];
#pragma unroll
  for (int i = 0; i < 4; ++i) acc[i] = (f32x4){0.f, 0.f, 0.f, 0.f};
  float zacc[4] = {0.f, 0.f, 0.f, 0.f};

  const u16* kh_ptr = KH + ((size_t)n * HW + w * 16 + l15) * CC + lg * 8;
  const u16* kl_ptr = KL + ((size_t)n * HW + w * 16 + l15) * CC + lg * 8;
  const u16* v_ptr = V + ((size_t)n * CC + l15) * HW + lg * 8;

  const int swz_w = (l15 & 7) << 3;   // write side: q&7 == l15&7
  const int qr = w * 16 + l15;        // PV read q-row
  const int swz_r = (qr & 7) << 3;

  // preload K(0)
  bf16x8 kh0 = *(const bf16x8*)(kh_ptr);
  bf16x8 kh1 = *(const bf16x8*)(kh_ptr + 32);
  bf16x8 kl0 = *(const bf16x8*)(kl_ptr);
  bf16x8 kl1 = *(const bf16x8*)(kl_ptr + 32);

  for (int t = 0; t < 64; ++t) {
    const int buf = t & 1;
    // early-issue V(t): consumed after the barrier, hidden under QK MFMAs
    bf16x8 vb[2][4];
#pragma unroll
    for (int m2 = 0; m2 < 2; ++m2)
#pragma unroll
      for (int chb = 0; chb < 4; ++chb)
        vb[m2][chb] =
            *(const bf16x8*)(v_ptr + (size_t)chb * 16 * HW + m2 * 32);
    // prefetch K(t+1); tail (t=63) reads land in the adjacent ws arrays
    // (mapped, values discarded)
    kh_ptr += 64 * CC;
    kl_ptr += 64 * CC;
    const bf16x8 nkh0 = *(const bf16x8*)(kh_ptr);
    const bf16x8 nkh1 = *(const bf16x8*)(kh_ptr + 32);
    const bf16x8 nkl0 = *(const bf16x8*)(kl_ptr);
    const bf16x8 nkl1 = *(const bf16x8*)(kl_ptr + 32);
#pragma unroll
    for (int qb = 0; qb < 4; ++qb) {
      f32x4 s = {0.f, 0.f, 0.f, 0.f};
      // S^T = K*Q with hi/lo error correction (drop Kl*Ql term)
      __builtin_amdgcn_s_setprio(1);
      s = __builtin_amdgcn_mfma_f32_16x16x32_bf16(kh0, qh[qb][0], s, 0, 0, 0);
      s = __builtin_amdgcn_mfma_f32_16x16x32_bf16(kh1, qh[qb][1], s, 0, 0, 0);
      s = __builtin_amdgcn_mfma_f32_16x16x32_bf16(kh0, ql[qb][0], s, 0, 0, 0);
      s = __builtin_amdgcn_mfma_f32_16x16x32_bf16(kh1, ql[qb][1], s, 0, 0, 0);
      s = __builtin_amdgcn_mfma_f32_16x16x32_bf16(kl0, qh[qb][0], s, 0, 0, 0);
      s = __builtin_amdgcn_mfma_f32_16x16x32_bf16(kl1, qh[qb][1], s, 0, 0, 0);
      __builtin_amdgcn_s_setprio(0);
      const float p0 = EXP2F(s[0]);
      const float p1 = EXP2F(s[1]);
      const float p2 = EXP2F(s[2]);
      const float p3 = EXP2F(s[3]);
      zacc[qb] += (p0 + p1) + (p2 + p3);
      const int qq = qb * 16 + l15;
      const int keyb = (w * 16 + lg * 4) ^ swz_w;
      u32* dst = (u32*)&P[buf][qq][keyb];
      dst[0] = (u32)f2bf(p0) | ((u32)f2bf(p1) << 16);
      dst[1] = (u32)f2bf(p2) | ((u32)f2bf(p3) << 16);
    }
    // barrier WITHOUT vmcnt drain: only LDS (P writes) must be visible;
    // K/V prefetches stay in flight across the barrier.
    asm volatile("s_waitcnt lgkmcnt(0)" ::: "memory");
    __builtin_amdgcn_s_barrier();
#pragma unroll
    for (int m2 = 0; m2 < 2; ++m2) {
      const int kb2 = (m2 * 32 + lg * 8) ^ swz_r;
      const bf16x8 pa = *(const bf16x8*)&P[buf][qr][kb2];
      __builtin_amdgcn_s_setprio(1);
#pragma unroll
      for (int chb = 0; chb < 4; ++chb)
        acc[chb] =
            __builtin_amdgcn_mfma_f32_16x16x32_bf16(pa, vb[m2][chb], acc[chb], 0, 0, 0);
      __builtin_amdgcn_s_setprio(0);
    }
    v_ptr += 64;
    kh0 = nkh0; kh1 = nkh1; kl0 = nkl0; kl1 = nkl1;
  }

  // Z: reduce row-groups (shfl) then waves (LDS); acc rows are complete
#pragma unroll
  for (int qb = 0; qb < 4; ++qb) {
    zacc[qb] += __shfl_xor(zacc[qb], 16);
    zacc[qb] += __shfl_xor(zacc[qb], 32);
  }
  if (l < 16) {
#pragma unroll
    for (int qb = 0; qb < 4; ++qb) ZB[w][qb * 16 + l] = zacc[qb];
  }
  __syncthreads();
  float* resn = RES + ((size_t)n * HW + q0) * CC;
#pragma unroll
  for (int r = 0; r < 4; ++r) {
    const int qq = w * 16 + lg * 4 + r;
    const float z = ZB[0][qq] + ZB[1][qq] + ZB[2][qq] + ZB[3][qq];
    const float rz = 1.0f / z;
#pragma unroll
    for (int chb = 0; chb < 4; ++chb)
      resn[(size_t)qq * CC + chb * 16 + l15] = acc[chb][r] * rz;
  }
}

// ---------- kernel 4: out = x + wo @ res(reshaped) + bo
// res[n] flat [i][ch] == [c2][h2][w2]; conv mixes c2.
__global__ __launch_bounds__(256) void k_out(const float* __restrict__ RES,
                                             const float* __restrict__ x,
                                             const float* __restrict__ wo,
                                             const float* __restrict__ bo,
                                             float* __restrict__ out) {
  const int n = blockIdx.x >> 4;
  const int j = ((blockIdx.x & 15) << 8) + threadIdx.x;  // h2*64+w2
  const float* rn = RES + (size_t)n * HW * CC;
  float rcol[CC];
#pragma unroll
  for (int c2 = 0; c2 < CC; ++c2) rcol[c2] = rn[(size_t)c2 * HW + j];
  const size_t xb = (size_t)n * CC * HW;
  for (int o = 0; o < CC; ++o) {
    float s = bo[o];
#pragma unroll
    for (int c2 = 0; c2 < CC; ++c2) s = fmaf(wo[o * CC + c2], rcol[c2], s);
    out[xb + (size_t)o * HW + j] = x[xb + (size_t)o * HW + j] + s;
  }
}

extern "C" void kernel_launch(void* const* d_in, const int* in_sizes, int n_in,
                              void* d_out, int out_size, void* d_ws,
                              size_t ws_size, hipStream_t stream) {
  const float* x = (const float*)d_in[0];
  const float* gamma = (const float*)d_in[1];
  const float* beta = (const float*)d_in[2];
  const float* wq = (const float*)d_in[3];
  const float* bq = (const float*)d_in[4];
  const float* wk = (const float*)d_in[5];
  const float* bk = (const float*)d_in[6];
  const float* wv = (const float*)d_in[7];
  const float* bv = (const float*)d_in[8];
  const float* wo = (const float*)d_in[9];
  const float* bo = (const float*)d_in[10];
  float* out = (float*)d_out;

  char* ws = (char*)d_ws;
  float* sab = (float*)ws;  // 128 f32
  const size_t ARR = (size_t)NBATCH * HW * CC;
  u16* QH = (u16*)(ws + 1024);
  u16* QL = QH + ARR;
  u16* KH = QL + ARR;
  u16* KL = KH + ARR;
  u16* V = KL + ARR;
  float* RES = (float*)(ws + 1024 + 5 * ARR * sizeof(u16));
  // total ws use: 1024 + 5*4MB + 8MB ~= 29.4 MB

  hipLaunchKernelGGL(k_stats, dim3(64), dim3(256), 0, stream, x, gamma, beta,
                     sab);
  hipLaunchKernelGGL(k_qkv, dim3(512), dim3(256), 0, stream, x, sab, wq, bq,
                     wk, bk, wv, bv, QH, QL, KH, KL, V);
  hipLaunchKernelGGL(k_attn, dim3(512), dim3(256), 0, stream, QH, QL, KH, KL,
                     V, RES);
  hipLaunchKernelGGL(k_out, dim3(128), dim3(256), 0, stream, RES, x, wo, bo,
                     out);
}